// Round 1
// baseline (4975.697 us; speedup 1.0000x reference)
//
#include <hip/hip_runtime.h>
#include <math.h>

#define NN 50000
#define EE 800000
#define HH 4
#define HC 128
#define GG 1000

static inline int ceil_div(int a, int b) { return (a + b - 1) / b; }

// monotonic float->uint encoding for atomicMax on floats
__device__ __forceinline__ unsigned enc_f(float f) {
    unsigned u = __float_as_uint(f);
    return (u & 0x80000000u) ? ~u : (u | 0x80000000u);
}
__device__ __forceinline__ float dec_f(unsigned u) {
    unsigned v = (u & 0x80000000u) ? (u & 0x7fffffffu) : ~u;
    return __uint_as_float(v);
}

struct GemmOut { const float* w; const float* b; float* out; };
struct GemmOuts { GemmOut o[4]; };

// out[n, 0:128] = x[n, 0:FIN] @ w[FIN,128] + b  for 4 (w,b,out) triples (blockIdx.y)
template<int FIN>
__global__ __launch_bounds__(256) void gemm_qkvs(const float* __restrict__ x, GemmOuts go)
{
    __shared__ float xs[64][FIN + 1];
    const int bn = blockIdx.x * 64;
    const int t = threadIdx.x;
    for (int p = t; p < 64 * (FIN / 4); p += 256) {
        int row = p / (FIN / 4), c4 = p % (FIN / 4);
        float4 val = make_float4(0.f, 0.f, 0.f, 0.f);
        if (bn + row < NN)
            val = reinterpret_cast<const float4*>(x)[(size_t)(bn + row) * (FIN / 4) + c4];
        xs[row][c4 * 4 + 0] = val.x; xs[row][c4 * 4 + 1] = val.y;
        xs[row][c4 * 4 + 2] = val.z; xs[row][c4 * 4 + 3] = val.w;
    }
    __syncthreads();
    const float* __restrict__ w = go.o[blockIdx.y].w;
    const float* __restrict__ b = go.o[blockIdx.y].b;
    float* __restrict__ out = go.o[blockIdx.y].out;
    const int tx = t & 15, ty = t >> 4;   // tx: 8-col group, ty: 4-node group
    float acc[4][8];
#pragma unroll
    for (int r = 0; r < 4; ++r)
#pragma unroll
        for (int c = 0; c < 8; ++c) acc[r][c] = 0.f;
#pragma unroll 4
    for (int kk = 0; kk < FIN; ++kk) {
        const float4 w0 = reinterpret_cast<const float4*>(w + kk * HC)[tx * 2];
        const float4 w1 = reinterpret_cast<const float4*>(w + kk * HC)[tx * 2 + 1];
        float xr[4];
#pragma unroll
        for (int r = 0; r < 4; ++r) xr[r] = xs[ty * 4 + r][kk];
#pragma unroll
        for (int r = 0; r < 4; ++r) {
            acc[r][0] += xr[r] * w0.x; acc[r][1] += xr[r] * w0.y;
            acc[r][2] += xr[r] * w0.z; acc[r][3] += xr[r] * w0.w;
            acc[r][4] += xr[r] * w1.x; acc[r][5] += xr[r] * w1.y;
            acc[r][6] += xr[r] * w1.z; acc[r][7] += xr[r] * w1.w;
        }
    }
    const float4 b0 = reinterpret_cast<const float4*>(b)[tx * 2];
    const float4 b1 = reinterpret_cast<const float4*>(b)[tx * 2 + 1];
#pragma unroll
    for (int r = 0; r < 4; ++r) {
        int node = bn + ty * 4 + r;
        if (node < NN) {
            float4 o0 = make_float4(acc[r][0] + b0.x, acc[r][1] + b0.y,
                                    acc[r][2] + b0.z, acc[r][3] + b0.w);
            float4 o1 = make_float4(acc[r][4] + b1.x, acc[r][5] + b1.y,
                                    acc[r][6] + b1.z, acc[r][7] + b1.w);
            reinterpret_cast<float4*>(out + (size_t)node * HC + tx * 8)[0] = o0;
            reinterpret_cast<float4*>(out + (size_t)node * HC + tx * 8)[1] = o1;
        }
    }
}

// per edge: alpha[e,h] = dot_c(q[dst,h,:], k[src,h,:] + eproj) / sqrt(32); atomicMax m[dst,h]
__global__ __launch_bounds__(256) void edge_alpha(
    const int* __restrict__ ei, const float* __restrict__ ea,
    const float* __restrict__ q, const float* __restrict__ k,
    const float* __restrict__ we, float* __restrict__ alpha,
    unsigned* __restrict__ m)
{
    __shared__ float4 we_s[128];   // we [4][128] as float4[4][32]
    const int t = threadIdx.x;
    if (t < 128) we_s[t] = reinterpret_cast<const float4*>(we)[t];
    __syncthreads();
    const int e = blockIdx.x * 8 + (t >> 5);
    if (e >= EE) return;
    const int lane = t & 31;
    const int src = ei[e], dst = ei[EE + e];
    const float4 av = reinterpret_cast<const float4*>(ea)[e];
    const float4 w0 = we_s[lane], w1 = we_s[32 + lane], w2 = we_s[64 + lane], w3 = we_s[96 + lane];
    float4 ep;
    ep.x = av.x * w0.x + av.y * w1.x + av.z * w2.x + av.w * w3.x;
    ep.y = av.x * w0.y + av.y * w1.y + av.z * w2.y + av.w * w3.y;
    ep.z = av.x * w0.z + av.y * w1.z + av.z * w2.z + av.w * w3.z;
    ep.w = av.x * w0.w + av.y * w1.w + av.z * w2.w + av.w * w3.w;
    const float4 q4 = reinterpret_cast<const float4*>(q)[(size_t)dst * 32 + lane];
    const float4 k4 = reinterpret_cast<const float4*>(k)[(size_t)src * 32 + lane];
    float p = q4.x * (k4.x + ep.x) + q4.y * (k4.y + ep.y)
            + q4.z * (k4.z + ep.z) + q4.w * (k4.w + ep.w);
    p += __shfl_xor(p, 1); p += __shfl_xor(p, 2); p += __shfl_xor(p, 4);
    if ((lane & 7) == 0) {
        const int head = lane >> 3;
        const float al = p * 0.17677669529663687f;   // 1/sqrt(32)
        alpha[(size_t)e * 4 + head] = al;
        atomicMax(&m[(size_t)dst * 4 + head], enc_f(al));
    }
}

// per edge: a = exp(alpha - m[dst]); s[dst,h] += a; hout[dst,:] += a*(v[src,:] + eproj)
__global__ __launch_bounds__(256) void edge_agg(
    const int* __restrict__ ei, const float* __restrict__ ea,
    const float* __restrict__ v, const float* __restrict__ we,
    const float* __restrict__ alpha, const unsigned* __restrict__ m,
    float* __restrict__ s, float* __restrict__ hout)
{
    __shared__ float4 we_s[128];
    const int t = threadIdx.x;
    if (t < 128) we_s[t] = reinterpret_cast<const float4*>(we)[t];
    __syncthreads();
    const int e = blockIdx.x * 8 + (t >> 5);
    if (e >= EE) return;
    const int lane = t & 31;
    const int src = ei[e], dst = ei[EE + e];
    const int head = lane >> 3;
    const float al = alpha[(size_t)e * 4 + head];
    const float mx = dec_f(m[(size_t)dst * 4 + head]);
    const float a = __expf(al - mx);
    if ((lane & 7) == 0) atomicAdd(&s[(size_t)dst * 4 + head], a);
    const float4 av = reinterpret_cast<const float4*>(ea)[e];
    const float4 w0 = we_s[lane], w1 = we_s[32 + lane], w2 = we_s[64 + lane], w3 = we_s[96 + lane];
    float4 ep;
    ep.x = av.x * w0.x + av.y * w1.x + av.z * w2.x + av.w * w3.x;
    ep.y = av.x * w0.y + av.y * w1.y + av.z * w2.y + av.w * w3.y;
    ep.z = av.x * w0.z + av.y * w1.z + av.z * w2.z + av.w * w3.z;
    ep.w = av.x * w0.w + av.y * w1.w + av.z * w2.w + av.w * w3.w;
    const float4 v4 = reinterpret_cast<const float4*>(v)[(size_t)src * 32 + lane];
    float* o = hout + (size_t)dst * HC + lane * 4;
    atomicAdd(o + 0, (v4.x + ep.x) * a);
    atomicAdd(o + 1, (v4.y + ep.y) * a);
    atomicAdd(o + 2, (v4.z + ep.z) * a);
    atomicAdd(o + 3, (v4.w + ep.w) * a);
}

__global__ __launch_bounds__(256) void combine(
    float* __restrict__ hout, const float* __restrict__ s,
    const float* __restrict__ sk, int relu)
{
    const int i = blockIdx.x * 256 + threadIdx.x;
    if (i >= NN * HC) return;
    const int node = i >> 7, c = i & 127, head = c >> 5;
    float val = hout[i] / (s[(size_t)node * 4 + head] + 1e-16f) + sk[i];
    if (relu) val = fmaxf(val, 0.f);
    hout[i] = val;
}

__global__ __launch_bounds__(256) void pool_accum(
    const float* __restrict__ h, const int* __restrict__ batch,
    float* __restrict__ pooled, float* __restrict__ cnt)
{
    const int i = blockIdx.x * 256 + threadIdx.x;
    if (i >= NN * HC) return;
    const int node = i >> 7, c = i & 127;
    const int g = batch[node];
    atomicAdd(&pooled[(size_t)g * HC + c], h[i]);
    if (c == 0) atomicAdd(&cnt[g], 1.0f);
}

__global__ __launch_bounds__(64) void head_k(
    const float* __restrict__ pooled, const float* __restrict__ cnt,
    const float* __restrict__ wlin, const float* __restrict__ blin,
    float* __restrict__ out)
{
    const int g = blockIdx.x;
    const int lane = threadIdx.x;
    float p = pooled[(size_t)g * HC + lane] * wlin[lane]
            + pooled[(size_t)g * HC + 64 + lane] * wlin[64 + lane];
#pragma unroll
    for (int off = 32; off; off >>= 1) p += __shfl_xor(p, off);
    if (lane == 0) out[g] = p / fmaxf(cnt[g], 1.0f) + blin[0];
}

extern "C" void kernel_launch(void* const* d_in, const int* in_sizes, int n_in,
                              void* d_out, int out_size, void* d_ws, size_t ws_size,
                              hipStream_t stream)
{
    const float* x    = (const float*)d_in[0];
    const int*   ei   = (const int*)d_in[1];
    const float* ea   = (const float*)d_in[2];
    const int*   batch = (const int*)d_in[3];
    auto W = [&](int i) { return (const float*)d_in[i]; };

    float* ws = (float*)d_ws;
    float* q      = ws;
    float* k      = q  + (size_t)NN * HC;
    float* v      = k  + (size_t)NN * HC;
    float* sk     = v  + (size_t)NN * HC;
    float* h1     = sk + (size_t)NN * HC;
    float* h2     = h1 + (size_t)NN * HC;
    float* alpha  = h2 + (size_t)NN * HC;
    unsigned* mbuf = (unsigned*)(alpha + (size_t)EE * HH);
    float* sbuf   = (float*)(mbuf + (size_t)NN * HH);
    float* pooled = sbuf + (size_t)NN * HH;
    float* cnt    = pooled + (size_t)GG * HC;

    auto layer = [&](const float* hin, int fin, float* hout, int relu, int wb) {
        hipMemsetAsync(hout, 0, (size_t)NN * HC * 4, stream);
        hipMemsetAsync(mbuf, 0, (size_t)NN * HH * 4, stream);
        hipMemsetAsync(sbuf, 0, (size_t)NN * HH * 4, stream);
        GemmOuts go = {{ { W(wb + 0), W(wb + 1), q  },
                         { W(wb + 2), W(wb + 3), k  },
                         { W(wb + 4), W(wb + 5), v  },
                         { W(wb + 7), W(wb + 8), sk } }};
        dim3 g1(ceil_div(NN, 64), 4);
        if (fin == 64) gemm_qkvs<64><<<g1, 256, 0, stream>>>(hin, go);
        else           gemm_qkvs<128><<<g1, 256, 0, stream>>>(hin, go);
        const float* we = W(wb + 6);
        edge_alpha<<<ceil_div(EE, 8), 256, 0, stream>>>(ei, ea, q, k, we, alpha, mbuf);
        edge_agg  <<<ceil_div(EE, 8), 256, 0, stream>>>(ei, ea, v, we, alpha, mbuf, sbuf, hout);
        combine   <<<ceil_div(NN * HC, 256), 256, 0, stream>>>(hout, sbuf, sk, relu);
    };

    layer(x,  64,  h1, 1, 4);
    layer(h1, 128, h2, 1, 13);
    layer(h2, 128, h1, 0, 22);

    hipMemsetAsync(pooled, 0, ((size_t)GG * HC + GG) * 4, stream);
    pool_accum<<<ceil_div(NN * HC, 256), 256, 0, stream>>>(h1, batch, pooled, cnt);
    head_k<<<GG, 64, 0, stream>>>(pooled, cnt, W(31), W(32), (float*)d_out);
}

// Round 2
// 833.876 us; speedup vs baseline: 5.9670x; 5.9670x over previous
//
#include <hip/hip_runtime.h>
#include <math.h>

#define NN 50000
#define EE 800000
#define HH 4
#define HC 128
#define GG 1000

static inline int ceil_div(int a, int b) { return (a + b - 1) / b; }

struct GemmOut { const float* w; const float* b; float* out; };
struct GemmOuts { GemmOut o[4]; };

// out[n, 0:128] = x[n, 0:FIN] @ w[FIN,128] + b  for 4 (w,b,out) triples (blockIdx.y)
template<int FIN>
__global__ __launch_bounds__(256) void gemm_qkvs(const float* __restrict__ x, GemmOuts go)
{
    __shared__ float xs[64][FIN + 1];
    const int bn = blockIdx.x * 64;
    const int t = threadIdx.x;
    for (int p = t; p < 64 * (FIN / 4); p += 256) {
        int row = p / (FIN / 4), c4 = p % (FIN / 4);
        float4 val = make_float4(0.f, 0.f, 0.f, 0.f);
        if (bn + row < NN)
            val = reinterpret_cast<const float4*>(x)[(size_t)(bn + row) * (FIN / 4) + c4];
        xs[row][c4 * 4 + 0] = val.x; xs[row][c4 * 4 + 1] = val.y;
        xs[row][c4 * 4 + 2] = val.z; xs[row][c4 * 4 + 3] = val.w;
    }
    __syncthreads();
    const float* __restrict__ w = go.o[blockIdx.y].w;
    const float* __restrict__ b = go.o[blockIdx.y].b;
    float* __restrict__ out = go.o[blockIdx.y].out;
    const int tx = t & 15, ty = t >> 4;
    float acc[4][8];
#pragma unroll
    for (int r = 0; r < 4; ++r)
#pragma unroll
        for (int c = 0; c < 8; ++c) acc[r][c] = 0.f;
#pragma unroll 4
    for (int kk = 0; kk < FIN; ++kk) {
        const float4 w0 = reinterpret_cast<const float4*>(w + kk * HC)[tx * 2];
        const float4 w1 = reinterpret_cast<const float4*>(w + kk * HC)[tx * 2 + 1];
        float xr[4];
#pragma unroll
        for (int r = 0; r < 4; ++r) xr[r] = xs[ty * 4 + r][kk];
#pragma unroll
        for (int r = 0; r < 4; ++r) {
            acc[r][0] += xr[r] * w0.x; acc[r][1] += xr[r] * w0.y;
            acc[r][2] += xr[r] * w0.z; acc[r][3] += xr[r] * w0.w;
            acc[r][4] += xr[r] * w1.x; acc[r][5] += xr[r] * w1.y;
            acc[r][6] += xr[r] * w1.z; acc[r][7] += xr[r] * w1.w;
        }
    }
    const float4 b0 = reinterpret_cast<const float4*>(b)[tx * 2];
    const float4 b1 = reinterpret_cast<const float4*>(b)[tx * 2 + 1];
#pragma unroll
    for (int r = 0; r < 4; ++r) {
        int node = bn + ty * 4 + r;
        if (node < NN) {
            float4 o0 = make_float4(acc[r][0] + b0.x, acc[r][1] + b0.y,
                                    acc[r][2] + b0.z, acc[r][3] + b0.w);
            float4 o1 = make_float4(acc[r][4] + b1.x, acc[r][5] + b1.y,
                                    acc[r][6] + b1.z, acc[r][7] + b1.w);
            reinterpret_cast<float4*>(out + (size_t)node * HC + tx * 8)[0] = o0;
            reinterpret_cast<float4*>(out + (size_t)node * HC + tx * 8)[1] = o1;
        }
    }
}

// ---------------- counting-sort of edges by dst ----------------

__global__ __launch_bounds__(256) void hist_k(const int* __restrict__ ei, int* __restrict__ cnt)
{
    int e = blockIdx.x * 256 + threadIdx.x;
    if (e >= EE) return;
    atomicAdd(&cnt[ei[EE + e]], 1);
}

__global__ __launch_bounds__(1024) void scan1_k(const int* __restrict__ cnt, int n,
                                                int* __restrict__ rowptr, int* __restrict__ bsum)
{
    __shared__ int tmp[1024];
    const int tid = threadIdx.x;
    const int i = blockIdx.x * 1024 + tid;
    tmp[tid] = (i < n) ? cnt[i] : 0;
    __syncthreads();
    for (int off = 1; off < 1024; off <<= 1) {
        int t = (tid >= off) ? tmp[tid - off] : 0;
        __syncthreads();
        tmp[tid] += t;
        __syncthreads();
    }
    if (i < n) rowptr[i + 1] = tmp[tid];
    if (tid == 1023) bsum[blockIdx.x] = tmp[1023];
}

__global__ void scan2_k(int* __restrict__ bsum, int nb)
{
    if (threadIdx.x == 0) {
        int run = 0;
        for (int i = 0; i < nb; ++i) { int t = bsum[i]; bsum[i] = run; run += t; }
    }
}

__global__ __launch_bounds__(1024) void scan3_k(int* __restrict__ rowptr,
                                                const int* __restrict__ bsum, int n)
{
    int i = blockIdx.x * 1024 + threadIdx.x;
    if (i < n) rowptr[i + 1] += bsum[blockIdx.x];
    if (i == 0) rowptr[0] = 0;
}

__global__ __launch_bounds__(256) void scatter_k(const int* __restrict__ ei,
                                                 int* __restrict__ wcur,
                                                 int* __restrict__ srcp,
                                                 int* __restrict__ eidx)
{
    int e = blockIdx.x * 256 + threadIdx.x;
    if (e >= EE) return;
    int dst = ei[EE + e];
    int pos = atomicAdd(&wcur[dst], 1);
    srcp[pos] = ei[e];
    eidx[pos] = e;
}

// ---------------- fused per-node attention aggregation ----------------
// one 32-lane group per dst node; online softmax; fused skip + relu
__global__ __launch_bounds__(256) void node_agg(
    const int* __restrict__ rowptr, const int* __restrict__ srcp,
    const int* __restrict__ eidx, const float* __restrict__ ea,
    const float* __restrict__ q, const float* __restrict__ k,
    const float* __restrict__ v, const float* __restrict__ we,
    const float* __restrict__ sk, float* __restrict__ hout, int relu)
{
    __shared__ float4 we_s[128];   // we [4][128] as float4[4][32]
    const int t = threadIdx.x;
    if (t < 128) we_s[t] = reinterpret_cast<const float4*>(we)[t];
    __syncthreads();
    const int node = blockIdx.x * 8 + (t >> 5);
    if (node >= NN) return;
    const int lane = t & 31;
    const int beg = rowptr[node], end = rowptr[node + 1];

    const float4 q4 = reinterpret_cast<const float4*>(q)[(size_t)node * 32 + lane];
    const float4 w0 = we_s[lane], w1 = we_s[32 + lane], w2 = we_s[64 + lane], w3 = we_s[96 + lane];

    float4 acc = make_float4(0.f, 0.f, 0.f, 0.f);
    float m = -INFINITY, s = 0.f;

    for (int p = beg; p < end; ++p) {
        const int src = srcp[p];
        const int e = eidx[p];
        const float4 av = reinterpret_cast<const float4*>(ea)[e];
        float4 ep;
        ep.x = av.x * w0.x + av.y * w1.x + av.z * w2.x + av.w * w3.x;
        ep.y = av.x * w0.y + av.y * w1.y + av.z * w2.y + av.w * w3.y;
        ep.z = av.x * w0.z + av.y * w1.z + av.z * w2.z + av.w * w3.z;
        ep.w = av.x * w0.w + av.y * w1.w + av.z * w2.w + av.w * w3.w;
        const float4 k4 = reinterpret_cast<const float4*>(k)[(size_t)src * 32 + lane];
        float al = q4.x * (k4.x + ep.x) + q4.y * (k4.y + ep.y)
                 + q4.z * (k4.z + ep.z) + q4.w * (k4.w + ep.w);
        al += __shfl_xor(al, 1); al += __shfl_xor(al, 2); al += __shfl_xor(al, 4);
        al *= 0.17677669529663687f;   // 1/sqrt(32)
        const float4 v4 = reinterpret_cast<const float4*>(v)[(size_t)src * 32 + lane];
        if (al > m) {                  // uniform within each 8-lane head group
            const float r = __expf(m - al);
            acc.x *= r; acc.y *= r; acc.z *= r; acc.w *= r;
            s *= r;
            m = al;
        }
        const float pe = __expf(al - m);
        s += pe;
        acc.x += pe * (v4.x + ep.x);
        acc.y += pe * (v4.y + ep.y);
        acc.z += pe * (v4.z + ep.z);
        acc.w += pe * (v4.w + ep.w);
    }
    const float inv = 1.0f / (s + 1e-16f);
    const float4 sk4 = reinterpret_cast<const float4*>(sk)[(size_t)node * 32 + lane];
    float4 o;
    o.x = acc.x * inv + sk4.x;
    o.y = acc.y * inv + sk4.y;
    o.z = acc.z * inv + sk4.z;
    o.w = acc.w * inv + sk4.w;
    if (relu) {
        o.x = fmaxf(o.x, 0.f); o.y = fmaxf(o.y, 0.f);
        o.z = fmaxf(o.z, 0.f); o.w = fmaxf(o.w, 0.f);
    }
    reinterpret_cast<float4*>(hout)[(size_t)node * 32 + lane] = o;
}

// ---------------- pooling + head (batch is sorted) ----------------

__global__ __launch_bounds__(256) void boundaries_k(const int* __restrict__ batch,
                                                    int* __restrict__ gptr)
{
    int i = blockIdx.x * 256 + threadIdx.x;
    if (i >= NN) return;
    int b = batch[i];
    int bp = (i == 0) ? -1 : batch[i - 1];
    for (int g = bp + 1; g <= b; ++g) gptr[g] = i;
    if (i == NN - 1) for (int g = b + 1; g <= GG; ++g) gptr[g] = NN;
}

__global__ __launch_bounds__(128) void head_k(
    const float* __restrict__ h, const int* __restrict__ gptr,
    const float* __restrict__ wlin, const float* __restrict__ blin,
    float* __restrict__ out)
{
    __shared__ float red[128];
    const int g = blockIdx.x;
    const int t = threadIdx.x;
    const int beg = gptr[g], end = gptr[g + 1];
    float p = 0.f;
    for (int n = beg; n < end; ++n) p += h[(size_t)n * HC + t];
    p *= wlin[t];
    red[t] = p;
    __syncthreads();
    for (int off = 64; off; off >>= 1) {
        if (t < off) red[t] += red[t + off];
        __syncthreads();
    }
    if (t == 0) out[g] = red[0] / fmaxf((float)(end - beg), 1.0f) + blin[0];
}

extern "C" void kernel_launch(void* const* d_in, const int* in_sizes, int n_in,
                              void* d_out, int out_size, void* d_ws, size_t ws_size,
                              hipStream_t stream)
{
    const float* x     = (const float*)d_in[0];
    const int*   ei    = (const int*)d_in[1];
    const float* ea    = (const float*)d_in[2];
    const int*   batch = (const int*)d_in[3];
    auto W = [&](int i) { return (const float*)d_in[i]; };

    float* ws = (float*)d_ws;
    float* q   = ws;
    float* k   = q  + (size_t)NN * HC;
    float* v   = k  + (size_t)NN * HC;
    float* sk  = v  + (size_t)NN * HC;
    float* h1  = sk + (size_t)NN * HC;
    float* h2  = h1 + (size_t)NN * HC;
    int* cnt    = (int*)(h2 + (size_t)NN * HC);
    int* rowptr = cnt + NN;            // NN+1
    int* wcur   = rowptr + NN + 1;     // NN
    int* srcp   = wcur + NN;           // EE
    int* eidx   = srcp + EE;           // EE
    int* gptr   = eidx + EE;           // GG+1
    int* bsum   = gptr + GG + 1;       // 64

    // ---- build CSR (every call; graph inputs are constant so work is identical) ----
    hipMemsetAsync(cnt, 0, NN * sizeof(int), stream);
    hist_k<<<ceil_div(EE, 256), 256, 0, stream>>>(ei, cnt);
    const int NB = ceil_div(NN, 1024);
    scan1_k<<<NB, 1024, 0, stream>>>(cnt, NN, rowptr, bsum);
    scan2_k<<<1, 64, 0, stream>>>(bsum, NB);
    scan3_k<<<NB, 1024, 0, stream>>>(rowptr, bsum, NN);
    hipMemcpyAsync(wcur, rowptr, NN * sizeof(int), hipMemcpyDeviceToDevice, stream);
    scatter_k<<<ceil_div(EE, 256), 256, 0, stream>>>(ei, wcur, srcp, eidx);

    auto layer = [&](const float* hin, int fin, float* hout, int relu, int wb) {
        GemmOuts go = {{ { W(wb + 0), W(wb + 1), q  },
                         { W(wb + 2), W(wb + 3), k  },
                         { W(wb + 4), W(wb + 5), v  },
                         { W(wb + 7), W(wb + 8), sk } }};
        dim3 g1(ceil_div(NN, 64), 4);
        if (fin == 64) gemm_qkvs<64><<<g1, 256, 0, stream>>>(hin, go);
        else           gemm_qkvs<128><<<g1, 256, 0, stream>>>(hin, go);
        node_agg<<<ceil_div(NN, 8), 256, 0, stream>>>(
            rowptr, srcp, eidx, ea, q, k, v, W(wb + 6), sk, hout, relu);
    };

    layer(x,  64,  h1, 1, 4);
    layer(h1, 128, h2, 1, 13);
    layer(h2, 128, h1, 0, 22);

    boundaries_k<<<ceil_div(NN, 256), 256, 0, stream>>>(batch, gptr);
    head_k<<<GG, 128, 0, stream>>>(h1, gptr, W(31), W(32), (float*)d_out);
}

// Round 3
// 525.943 us; speedup vs baseline: 9.4605x; 1.5855x over previous
//
#include <hip/hip_runtime.h>
#include <math.h>

#define NN 50000
#define EE 800000
#define GG 1000

typedef __attribute__((ext_vector_type(4))) _Float16 h4f;
typedef __attribute__((ext_vector_type(4))) float f32x4;

static inline int ceil_div(int a, int b) { return (a + b - 1) / b; }

// ---------------- counting-sort of edges by dst (+ ea permute) ----------------

__global__ __launch_bounds__(256) void hist_k(const int* __restrict__ ei, int* __restrict__ cnt)
{
    int e = blockIdx.x * 256 + threadIdx.x;
    if (e >= EE) return;
    atomicAdd(&cnt[ei[EE + e]], 1);
}

__global__ __launch_bounds__(1024) void scan1_k(const int* __restrict__ cnt, int n,
                                                int* __restrict__ rowptr, int* __restrict__ bsum)
{
    __shared__ int tmp[1024];
    const int tid = threadIdx.x;
    const int i = blockIdx.x * 1024 + tid;
    tmp[tid] = (i < n) ? cnt[i] : 0;
    __syncthreads();
    for (int off = 1; off < 1024; off <<= 1) {
        int t = (tid >= off) ? tmp[tid - off] : 0;
        __syncthreads();
        tmp[tid] += t;
        __syncthreads();
    }
    if (i < n) rowptr[i + 1] = tmp[tid];
    if (tid == 1023) bsum[blockIdx.x] = tmp[1023];
}

__global__ void scan2_k(int* __restrict__ bsum, int nb)
{
    if (threadIdx.x == 0) {
        int run = 0;
        for (int i = 0; i < nb; ++i) { int t = bsum[i]; bsum[i] = run; run += t; }
    }
}

__global__ __launch_bounds__(1024) void scan3_k(int* __restrict__ rowptr,
                                                const int* __restrict__ bsum, int n)
{
    int i = blockIdx.x * 1024 + threadIdx.x;
    if (i < n) rowptr[i + 1] += bsum[blockIdx.x];
    if (i == 0) rowptr[0] = 0;
}

__global__ __launch_bounds__(256) void scatter_k(const int* __restrict__ ei,
                                                 const float4* __restrict__ ea,
                                                 int* __restrict__ wcur,
                                                 int* __restrict__ srcp,
                                                 float4* __restrict__ ea_s)
{
    int e = blockIdx.x * 256 + threadIdx.x;
    if (e >= EE) return;
    int dst = ei[EE + e];
    int pos = atomicAdd(&wcur[dst], 1);
    srcp[pos] = ei[e];
    ea_s[pos] = ea[e];
}

// ---------------- f32 -> f16 convert ----------------

__global__ __launch_bounds__(256) void cvt_h(const float* __restrict__ in,
                                             _Float16* __restrict__ out, int n4)
{
    int i = blockIdx.x * 256 + threadIdx.x;
    if (i >= n4) return;
    float4 v = reinterpret_cast<const float4*>(in)[i];
    h4f h = {(_Float16)v.x, (_Float16)v.y, (_Float16)v.z, (_Float16)v.w};
    reinterpret_cast<h4f*>(out)[i] = h;
}

// ---------------- weight shuffle into MFMA fragment order ----------------
// wshuf[m][((s*8+c16)*64+lane)*4+j] = w_m[s*16 + (lane>>4)*4 + j][c16*16 + (lane&15)]
struct W4 { const float* w[4]; };

__global__ __launch_bounds__(64) void shuffle_w(W4 ws4, int K, _Float16* __restrict__ out)
{
    const int m = blockIdx.y;
    const int s = blockIdx.x >> 3, c16 = blockIdx.x & 7;
    const int lane = threadIdx.x;
    const float* __restrict__ w = ws4.w[m];
    const int kbase = s * 16 + (lane >> 4) * 4;
    const int col = c16 * 16 + (lane & 15);
    h4f h;
#pragma unroll
    for (int j = 0; j < 4; ++j) h[j] = (_Float16)w[(size_t)(kbase + j) * 128 + col];
    reinterpret_cast<h4f*>(out + (size_t)m * K * 128)[(size_t)blockIdx.x * 64 + lane] = h;
}

// ---------------- fused 4-matrix MFMA GEMM ----------------
// y=0: q (f32) + sk (f32);  y=1: k (f16) + v (f16)
template<int K>
__global__ __launch_bounds__(256) void gemm_mfma(
    const _Float16* __restrict__ xh, const _Float16* __restrict__ wshuf,
    const float* __restrict__ bq, const float* __restrict__ bk,
    const float* __restrict__ bv, const float* __restrict__ bs,
    float* __restrict__ qout, _Float16* __restrict__ kout,
    _Float16* __restrict__ vout, float* __restrict__ skout)
{
    constexpr int KS = K / 16;
    const int wid = threadIdx.x >> 6, lane = threadIdx.x & 63;
    const int row0 = blockIdx.x * 64 + wid * 16;
    const int y = blockIdx.y;
    const int arow = row0 + (lane & 15);
    const int ko = (lane >> 4) * 4;
    h4f a[KS];
    const bool rv = arow < NN;
#pragma unroll
    for (int s = 0; s < KS; ++s) {
        h4f t = {0, 0, 0, 0};
        if (rv) t = *reinterpret_cast<const h4f*>(&xh[(size_t)arow * K + s * 16 + ko]);
        a[s] = t;
    }
    const _Float16* __restrict__ wA = wshuf + (size_t)(y ? 1 : 0) * K * 128;
    const _Float16* __restrict__ wB = wshuf + (size_t)(y ? 2 : 3) * K * 128;
    const float* __restrict__ bA = y ? bk : bq;
    const float* __restrict__ bB = y ? bv : bs;
    f32x4 accA[8], accB[8];
#pragma unroll
    for (int c = 0; c < 8; ++c) { accA[c] = {0, 0, 0, 0}; accB[c] = {0, 0, 0, 0}; }
#pragma unroll
    for (int c = 0; c < 8; ++c)
#pragma unroll
        for (int s = 0; s < KS; ++s) {
            h4f ba = reinterpret_cast<const h4f*>(wA)[(s * 8 + c) * 64 + lane];
            h4f bb = reinterpret_cast<const h4f*>(wB)[(s * 8 + c) * 64 + lane];
            accA[c] = __builtin_amdgcn_mfma_f32_16x16x16f16(a[s], ba, accA[c], 0, 0, 0);
            accB[c] = __builtin_amdgcn_mfma_f32_16x16x16f16(a[s], bb, accB[c], 0, 0, 0);
        }
    const int orow0 = row0 + (lane >> 4) * 4;
    const int ocol = lane & 15;
#pragma unroll
    for (int c = 0; c < 8; ++c) {
        const int col = c * 16 + ocol;
        const float bAv = bA[col], bBv = bB[col];
#pragma unroll
        for (int r = 0; r < 4; ++r) {
            const int row = orow0 + r;
            if (row < NN) {
                if (y) {
                    kout[(size_t)row * 128 + col] = (_Float16)(accA[c][r] + bAv);
                    vout[(size_t)row * 128 + col] = (_Float16)(accB[c][r] + bBv);
                } else {
                    qout[(size_t)row * 128 + col]  = accA[c][r] + bAv;
                    skout[(size_t)row * 128 + col] = accB[c][r] + bBv;
                }
            }
        }
    }
}

// ---------------- fused per-node attention aggregation ----------------

__device__ __forceinline__ float4 eproj(const float4 av, const float4 w0,
                                        const float4 w1, const float4 w2, const float4 w3)
{
    float4 e;
    e.x = av.x * w0.x + av.y * w1.x + av.z * w2.x + av.w * w3.x;
    e.y = av.x * w0.y + av.y * w1.y + av.z * w2.y + av.w * w3.y;
    e.z = av.x * w0.z + av.y * w1.z + av.z * w2.z + av.w * w3.z;
    e.w = av.x * w0.w + av.y * w1.w + av.z * w2.w + av.w * w3.w;
    return e;
}

__global__ __launch_bounds__(256) void node_agg(
    const int* __restrict__ rowptr, const int* __restrict__ srcp,
    const float4* __restrict__ ea_s,
    const float* __restrict__ q, const _Float16* __restrict__ kh,
    const _Float16* __restrict__ vh, const float* __restrict__ we,
    const float* __restrict__ sk, float* __restrict__ hout,
    _Float16* __restrict__ houth, int relu)
{
    __shared__ float4 we_s[128];
    const int t = threadIdx.x;
    if (t < 128) we_s[t] = reinterpret_cast<const float4*>(we)[t];
    __syncthreads();
    const int node = blockIdx.x * 8 + (t >> 5);
    if (node >= NN) return;
    const int lane = t & 31;
    const int beg = rowptr[node], end = rowptr[node + 1];
    const float4 q4 = reinterpret_cast<const float4*>(q)[(size_t)node * 32 + lane];
    const float4 w0 = we_s[lane], w1 = we_s[32 + lane], w2 = we_s[64 + lane], w3 = we_s[96 + lane];

    float4 acc = make_float4(0.f, 0.f, 0.f, 0.f);
    float m = -INFINITY, s = 0.f;

    int p = beg;
    for (; p + 1 < end; p += 2) {
        const int sA = srcp[p], sB = srcp[p + 1];
        const float4 avA = ea_s[p], avB = ea_s[p + 1];
        const h4f kA = *reinterpret_cast<const h4f*>(&kh[(size_t)sA * 128 + lane * 4]);
        const h4f kB = *reinterpret_cast<const h4f*>(&kh[(size_t)sB * 128 + lane * 4]);
        const h4f vA = *reinterpret_cast<const h4f*>(&vh[(size_t)sA * 128 + lane * 4]);
        const h4f vB = *reinterpret_cast<const h4f*>(&vh[(size_t)sB * 128 + lane * 4]);
        const float4 eA = eproj(avA, w0, w1, w2, w3);
        const float4 eB = eproj(avB, w0, w1, w2, w3);
        float alA = q4.x * ((float)kA[0] + eA.x) + q4.y * ((float)kA[1] + eA.y)
                  + q4.z * ((float)kA[2] + eA.z) + q4.w * ((float)kA[3] + eA.w);
        float alB = q4.x * ((float)kB[0] + eB.x) + q4.y * ((float)kB[1] + eB.y)
                  + q4.z * ((float)kB[2] + eB.z) + q4.w * ((float)kB[3] + eB.w);
        alA += __shfl_xor(alA, 1); alA += __shfl_xor(alA, 2); alA += __shfl_xor(alA, 4);
        alB += __shfl_xor(alB, 1); alB += __shfl_xor(alB, 2); alB += __shfl_xor(alB, 4);
        alA *= 0.17677669529663687f;
        alB *= 0.17677669529663687f;
        const float mn = fmaxf(m, fmaxf(alA, alB));
        const float r  = __expf(m - mn);
        const float pA = __expf(alA - mn), pB = __expf(alB - mn);
        s = s * r + pA + pB;
        acc.x = acc.x * r + pA * ((float)vA[0] + eA.x) + pB * ((float)vB[0] + eB.x);
        acc.y = acc.y * r + pA * ((float)vA[1] + eA.y) + pB * ((float)vB[1] + eB.y);
        acc.z = acc.z * r + pA * ((float)vA[2] + eA.z) + pB * ((float)vB[2] + eB.z);
        acc.w = acc.w * r + pA * ((float)vA[3] + eA.w) + pB * ((float)vB[3] + eB.w);
        m = mn;
    }
    if (p < end) {
        const int sA = srcp[p];
        const float4 avA = ea_s[p];
        const h4f kA = *reinterpret_cast<const h4f*>(&kh[(size_t)sA * 128 + lane * 4]);
        const h4f vA = *reinterpret_cast<const h4f*>(&vh[(size_t)sA * 128 + lane * 4]);
        const float4 eA = eproj(avA, w0, w1, w2, w3);
        float alA = q4.x * ((float)kA[0] + eA.x) + q4.y * ((float)kA[1] + eA.y)
                  + q4.z * ((float)kA[2] + eA.z) + q4.w * ((float)kA[3] + eA.w);
        alA += __shfl_xor(alA, 1); alA += __shfl_xor(alA, 2); alA += __shfl_xor(alA, 4);
        alA *= 0.17677669529663687f;
        const float mn = fmaxf(m, alA);
        const float r  = __expf(m - mn);
        const float pA = __expf(alA - mn);
        s = s * r + pA;
        acc.x = acc.x * r + pA * ((float)vA[0] + eA.x);
        acc.y = acc.y * r + pA * ((float)vA[1] + eA.y);
        acc.z = acc.z * r + pA * ((float)vA[2] + eA.z);
        acc.w = acc.w * r + pA * ((float)vA[3] + eA.w);
        m = mn;
    }
    const float inv = 1.0f / (s + 1e-16f);
    const float4 sk4 = reinterpret_cast<const float4*>(sk)[(size_t)node * 32 + lane];
    float4 o;
    o.x = acc.x * inv + sk4.x;
    o.y = acc.y * inv + sk4.y;
    o.z = acc.z * inv + sk4.z;
    o.w = acc.w * inv + sk4.w;
    if (relu) {
        o.x = fmaxf(o.x, 0.f); o.y = fmaxf(o.y, 0.f);
        o.z = fmaxf(o.z, 0.f); o.w = fmaxf(o.w, 0.f);
    }
    reinterpret_cast<float4*>(hout)[(size_t)node * 32 + lane] = o;
    h4f oh = {(_Float16)o.x, (_Float16)o.y, (_Float16)o.z, (_Float16)o.w};
    reinterpret_cast<h4f*>(houth)[(size_t)node * 32 + lane] = oh;
}

// ---------------- pooling + head (batch is sorted) ----------------

__global__ __launch_bounds__(256) void boundaries_k(const int* __restrict__ batch,
                                                    int* __restrict__ gptr)
{
    int i = blockIdx.x * 256 + threadIdx.x;
    if (i >= NN) return;
    int b = batch[i];
    int bp = (i == 0) ? -1 : batch[i - 1];
    for (int g = bp + 1; g <= b; ++g) gptr[g] = i;
    if (i == NN - 1) for (int g = b + 1; g <= GG; ++g) gptr[g] = NN;
}

__global__ __launch_bounds__(128) void head_k(
    const float* __restrict__ h, const int* __restrict__ gptr,
    const float* __restrict__ wlin, const float* __restrict__ blin,
    float* __restrict__ out)
{
    __shared__ float red[128];
    const int g = blockIdx.x;
    const int t = threadIdx.x;
    const int beg = gptr[g], end = gptr[g + 1];
    float p = 0.f;
    for (int n = beg; n < end; ++n) p += h[(size_t)n * 128 + t];
    p *= wlin[t];
    red[t] = p;
    __syncthreads();
    for (int off = 64; off; off >>= 1) {
        if (t < off) red[t] += red[t + off];
        __syncthreads();
    }
    if (t == 0) out[g] = red[0] / fmaxf((float)(end - beg), 1.0f) + blin[0];
}

extern "C" void kernel_launch(void* const* d_in, const int* in_sizes, int n_in,
                              void* d_out, int out_size, void* d_ws, size_t ws_size,
                              hipStream_t stream)
{
    const float* x     = (const float*)d_in[0];
    const int*   ei    = (const int*)d_in[1];
    const float* ea    = (const float*)d_in[2];
    const int*   batch = (const int*)d_in[3];
    auto W = [&](int i) { return (const float*)d_in[i]; };

    char* wsb = (char*)d_ws;
    size_t off = 0;
    auto alloc = [&](size_t bytes) { void* p = wsb + off; off += (bytes + 15) & ~15ull; return p; };

    float* q    = (float*)alloc((size_t)NN * 128 * 4);
    float* sk   = (float*)alloc((size_t)NN * 128 * 4);
    float* h1   = (float*)alloc((size_t)NN * 128 * 4);
    float* h2   = (float*)alloc((size_t)NN * 128 * 4);
    float4* eaS = (float4*)alloc((size_t)EE * 16);
    _Float16* kh    = (_Float16*)alloc((size_t)NN * 128 * 2);
    _Float16* vh    = (_Float16*)alloc((size_t)NN * 128 * 2);
    _Float16* hh    = (_Float16*)alloc((size_t)NN * 128 * 2);
    _Float16* wshuf = (_Float16*)alloc((size_t)4 * 128 * 128 * 2);
    int* cnt    = (int*)alloc((size_t)NN * 4);
    int* rowptr = (int*)alloc((size_t)(NN + 1) * 4);
    int* wcur   = (int*)alloc((size_t)NN * 4);
    int* srcp   = (int*)alloc((size_t)EE * 4);
    int* gptr   = (int*)alloc((size_t)(GG + 1) * 4);
    int* bsum   = (int*)alloc((size_t)64 * 4);

    // ---- CSR build + ea permute ----
    hipMemsetAsync(cnt, 0, NN * sizeof(int), stream);
    hist_k<<<ceil_div(EE, 256), 256, 0, stream>>>(ei, cnt);
    const int NB = ceil_div(NN, 1024);
    scan1_k<<<NB, 1024, 0, stream>>>(cnt, NN, rowptr, bsum);
    scan2_k<<<1, 64, 0, stream>>>(bsum, NB);
    scan3_k<<<NB, 1024, 0, stream>>>(rowptr, bsum, NN);
    hipMemcpyAsync(wcur, rowptr, NN * sizeof(int), hipMemcpyDeviceToDevice, stream);
    scatter_k<<<ceil_div(EE, 256), 256, 0, stream>>>(ei, (const float4*)ea, wcur, srcp, eaS);

    // layer-1 input in f16
    cvt_h<<<ceil_div(NN * 64 / 4, 256), 256, 0, stream>>>(x, hh, NN * 64 / 4);
    boundaries_k<<<ceil_div(NN, 256), 256, 0, stream>>>(batch, gptr);

    auto layer = [&](int K, float* hout, int relu, int wb) {
        W4 w4 = {{ W(wb + 0), W(wb + 2), W(wb + 4), W(wb + 7) }};   // q,k,v,s
        shuffle_w<<<dim3((K / 16) * 8, 4), 64, 0, stream>>>(w4, K, wshuf);
        dim3 gg(ceil_div(NN, 64), 2);
        if (K == 64)
            gemm_mfma<64><<<gg, 256, 0, stream>>>(hh, wshuf, W(wb + 1), W(wb + 3),
                                                  W(wb + 5), W(wb + 8), q, kh, vh, sk);
        else
            gemm_mfma<128><<<gg, 256, 0, stream>>>(hh, wshuf, W(wb + 1), W(wb + 3),
                                                   W(wb + 5), W(wb + 8), q, kh, vh, sk);
        node_agg<<<ceil_div(NN, 8), 256, 0, stream>>>(
            rowptr, srcp, eaS, q, kh, vh, W(wb + 6), sk, hout, hh, relu);
    };

    layer(64,  h1, 1, 4);
    layer(128, h2, 1, 13);
    layer(128, h1, 0, 22);

    head_k<<<GG, 128, 0, stream>>>(h1, gptr, W(31), W(32), (float*)d_out);
}